// Round 16
// baseline (122.284 us; speedup 1.0000x reference)
//
#include <hip/hip_runtime.h>

// ---------------- types / helpers ----------------
typedef __attribute__((ext_vector_type(8))) __bf16 bf16x8;
typedef __attribute__((ext_vector_type(8))) short short8;
typedef __attribute__((ext_vector_type(4))) float f32x4;
typedef unsigned int u32;

static __device__ __forceinline__ unsigned short f2bf(float f) {
    u32 u = __float_as_uint(f);
    u += 0x7FFFu + ((u >> 16) & 1u);
    return (unsigned short)(u >> 16);
}
static __device__ __forceinline__ u32 cvt_pk_bf16(float lo, float hi) {
    u32 r;
    asm("v_cvt_pk_bf16_f32 %0, %1, %2" : "=v"(r) : "v"(lo), "v"(hi));
    return r;
}
static __device__ __forceinline__ bf16x8 as_bf16x8(short8 v) {
    return __builtin_bit_cast(bf16x8, v);
}
static __device__ __forceinline__ f32x4 mfma16(short8 a, short8 b, f32x4 c) {
    return __builtin_amdgcn_mfma_f32_16x16x32_bf16(as_bf16x8(a), as_bf16x8(b), c, 0, 0, 0);
}

// problem sizes
#define NB 8
#define NS 5
#define NQ 15
// ws layout (floats / bytes)
#define A_OFF_F 0
#define B_OFF_F (640*256)                        // 163840
#define XF_OFF_F (B_OFF_F + 1920*256)            // 655360
#define WF_OFF_BYTES ((XF_OFF_F + 600*1024)*4)   // 5079040, 16B aligned
#define WF1_OFF_BYTES (WF_OFF_BYTES + 48*8192)   // W1 frags (32 x 9216)
#define WFF_OFF_BYTES (WF1_OFF_BYTES + 32*9216)  // fw1/fw2 frags (32 x 8192)
#define WF3_OFF_BYTES (WFF_OFF_BYTES + 32*8192)  // fw3 frags (2 x 8192)

// ---------------- kernel A: W1 fragments only (needed by kB) ----------------
__global__ void kA(const float* __restrict__ w1, unsigned short* __restrict__ wf1) {
    int c1 = blockIdx.x;               // S*16 + tt
    int l = threadIdx.x;
    int S = c1 >> 4, tt = c1 & 15;
    int nn = tt * 16 + (l & 15);
    for (int kk = 0; kk < 9; ++kk) {
        int k0 = kk * 32 + (l >> 4) * 8;
        short8 ov;
        #pragma unroll
        for (int j = 0; j < 8; ++j) {
            int kb = k0 + j;
            float v = (kb < 258) ? w1[(size_t)(S * 258 + kb) * 256 + nn] : 0.0f;
            ov[j] = (short)f2bf(v);
        }
        *(short8*)((char*)wf1 + (size_t)c1 * 9216 + kk * 1024 + l * 16) = ov;
    }
}

// ---------------- kernel B: layer-1 via MFMA (1 cell/block) + all later-stage frags ----
// (verified round 15, unchanged)
__global__ void kB(const float* __restrict__ sup, const float* __restrict__ qry,
                   const unsigned short* __restrict__ wf1, const float* __restrict__ gb1,
                   const float* __restrict__ w2, const float* __restrict__ w3,
                   const float* __restrict__ w4,
                   const float* __restrict__ fw1, const float* __restrict__ fw2,
                   const float* __restrict__ fw3,
                   float* __restrict__ ws, unsigned short* __restrict__ wf,
                   unsigned short* __restrict__ wff, unsigned short* __restrict__ wf3,
                   float* __restrict__ out) {
    __shared__ short Xf[4608];        // 9 KB
    int bid = blockIdx.x;
    int t = threadIdx.x;
    int w = t >> 6, l = t & 63;
    int g = l >> 4, c = l & 15;

    if (bid >= 160) {
        if (bid < 172) {
            int cid = (bid - 160) * 4 + w;
            int L = cid >> 4, tt = cid & 15;
            const float* W = (L == 0) ? w2 : ((L == 1) ? w3 : w4);
            int nn = tt * 16 + (l & 15);
            #pragma unroll
            for (int kk = 0; kk < 8; ++kk) {
                int k0 = kk * 32 + (l >> 4) * 8;
                short8 ov;
                #pragma unroll
                for (int j = 0; j < 8; ++j)
                    ov[j] = (short)f2bf(W[(size_t)(k0 + j) * 256 + nn]);
                *(short8*)((char*)wf + (size_t)cid * 8192 + kk * 1024 + l * 16) = ov;
            }
        } else if (bid == 172) {
            if (w < 2) {
                int tt = w;
                int nn = tt * 16 + (l & 15);
                #pragma unroll
                for (int kk = 0; kk < 8; ++kk) {
                    int k0 = kk * 32 + (l >> 4) * 8;
                    short8 ov;
                    #pragma unroll
                    for (int j = 0; j < 8; ++j) {
                        float v = (nn < 29) ? fw3[(size_t)(k0 + j) * 29 + nn] : 0.0f;
                        ov[j] = (short)f2bf(v);
                    }
                    *(short8*)((char*)wf3 + (size_t)tt * 8192 + kk * 1024 + l * 16) = ov;
                }
            } else if (w == 2 && l == 0) {
                out[0] = 0.0f;
            }
        } else {
            int cid = (bid - 173) * 4 + w;
            int Lf = cid >> 4, tt = cid & 15;
            const float* W = (Lf == 0) ? fw1 : fw2;
            int nn = tt * 16 + (l & 15);
            #pragma unroll
            for (int kk = 0; kk < 8; ++kk) {
                int k0 = kk * 32 + (l >> 4) * 8;
                short8 ov;
                #pragma unroll
                for (int j = 0; j < 8; ++j)
                    ov[j] = (short)f2bf(W[(size_t)(k0 + j) * 256 + nn]);
                *(short8*)((char*)wff + (size_t)cid * 8192 + kk * 1024 + l * 16) = ov;
            }
        }
        return;
    }

    bool isA = (bid < 40);
    int S = isA ? 0 : 1;
    int cell = isA ? bid : (bid - 40);
    const float* src = (isA ? sup : qry) + (size_t)cell * 4096;
    float* dst0 = ws + (isA ? A_OFF_F : B_OFF_F);
    char* Xb = (char*)Xf;

    for (int kk = w; kk < 9; kk += 4) {
        int kbase = kk * 32 + g * 8;
        float v[8];
        #pragma unroll
        for (int j = 0; j < 8; ++j) {
            int kb = kbase + j;
            float x;
            if (kb < 256)       x = src[(size_t)kb * 16 + c];
            else if (kb == 256) x = (float)(c >> 2) * 0.25f;
            else if (kb == 257) x = (float)(c & 3) * 0.25f;
            else                x = 0.0f;
            v[j] = x;
        }
        uint4 hv;
        hv.x = cvt_pk_bf16(v[0], v[1]);
        hv.y = cvt_pk_bf16(v[2], v[3]);
        hv.z = cvt_pk_bf16(v[4], v[5]);
        hv.w = cvt_pk_bf16(v[6], v[7]);
        *(uint4*)(Xb + (size_t)kk * 1024 + l * 16) = hv;
    }
    __syncthreads();

    const char* wbase = (const char*)wf1 + (size_t)(S * 16 + w * 4) * 9216;
    short8 wcur[4];
    #pragma unroll
    for (int tti = 0; tti < 4; ++tti)
        wcur[tti] = *(const short8*)(wbase + (size_t)tti * 9216 + l * 16);

    f32x4 acc[4];
    #pragma unroll
    for (int tti = 0; tti < 4; ++tti) acc[tti] = (f32x4){0.f, 0.f, 0.f, 0.f};

    #pragma unroll
    for (int kk = 0; kk < 9; ++kk) {
        int kn = kk + 1; if (kn > 8) kn = 8;
        short8 wnxt[4];
        #pragma unroll
        for (int tti = 0; tti < 4; ++tti)
            wnxt[tti] = *(const short8*)(wbase + (size_t)tti * 9216 + kn * 1024 + l * 16);
        short8 h = *(const short8*)(Xb + (size_t)kk * 1024 + l * 16);
        #pragma unroll
        for (int tti = 0; tti < 4; ++tti)
            acc[tti] = mfma16(wcur[tti], h, acc[tti]);
        #pragma unroll
        for (int tti = 0; tti < 4; ++tti) wcur[tti] = wnxt[tti];
    }

    #pragma unroll
    for (int tti = 0; tti < 4; ++tti) {
        int col0 = w * 64 + tti * 16 + g * 4;
        float4 bv = {0.f, 0.f, 0.f, 0.f};
        if (S == 0) bv = *(const float4*)(gb1 + col0);
        int row = cell * 16 + c;
        float4 o;
        o.x = acc[tti][0] + bv.x;
        o.y = acc[tti][1] + bv.y;
        o.z = acc[tti][2] + bv.z;
        o.w = acc[tti][3] + bv.w;
        *(float4*)(dst0 + (size_t)row * 256 + col0) = o;
    }
}

// ---------------- kernel 3: g-MLP layers 2..4 (async W staging, 64-pair blocks) ---------
// grid = 2400 = (cell, quarter), 256 thr = 4 waves. Wave w: outcols [w*64,+64),
// all 64 pairs. H 32KB (R13-verified layout). W: global_load_lds into 3x16KB
// rotating LDS buffers, per-WAVE-private slices (wave w stages tt=4w..4w+3 = the
// frags it consumes -> no cross-wave sync; own-wave counted vmcnt only).
// Issue depth 2 steps (~2x step latency cover). LDS = 32+48 = 80KB exactly
// -> 2 blocks/CU (biases live in registers). Barriers: 1 phase-1 + 2 per inner
// layer boundary (raw s_barrier + manual lgkmcnt; never drain vmcnt to 0 mid-loop).
__launch_bounds__(256, 2)
__global__ void k3_g(const float* __restrict__ wsA, const float* __restrict__ wsB,
                     const unsigned short* __restrict__ wf,
                     const float* __restrict__ gb2, const float* __restrict__ gb3,
                     const float* __restrict__ gb4, float* __restrict__ xf) {
    __shared__ short Hf[16384];      // 32 KB: frag(m,kk) at (m*8+kk)*1024, m 0..3
    __shared__ short Wl[24576];      // 48 KB: 3 x 16KB step buffers
    int bid = blockIdx.x;
    int bqs = bid >> 2, quarter = bid & 3;
    int b = bqs / 75, rem = bqs % 75, qi = rem / 5, si = rem % 5;
    int t = threadIdx.x;
    int w = t >> 6, l = t & 63;
    int g = l >> 4, c = l & 15;
    char* Hb = (char*)Hf;
    char* Wb = (char*)Wl;
    const char* wfb = (const char*)wf;

    // stage step s's W slice for this wave (4 x 1KB frags, tt = 4w..4w+3)
    auto stage = [&](int s) {
        const char* src = wfb + (size_t)((s >> 3) * 16 + w * 4) * 8192
                              + (size_t)(s & 7) * 1024 + (size_t)l * 16;
        char* dst = Wb + (s % 3) * 16384 + w * 4096;
        #pragma unroll
        for (int i = 0; i < 4; ++i)
            __builtin_amdgcn_global_load_lds(
                (const __attribute__((address_space(1))) unsigned int*)(src + i * 8192),
                (__attribute__((address_space(3))) unsigned int*)(dst + i * 1024),
                16, 0, 0);
    };

    stage(0);
    stage(1);

    // ---- phase 1 (R13-verified): wave w fills frag m=w; support col = c,
    // query row = quarter*4 + w; k = kk*32 + g*8 + j.
    {
        const float* Arow = wsA + (size_t)(b * NS + si) * 4096 + c * 256;
        const float* Brow = wsB + (size_t)(b * NQ + qi) * 4096 + (quarter * 4 + w) * 256;
        #pragma unroll
        for (int kk = 0; kk < 8; ++kk) {
            const float* ap = Arow + kk * 32 + g * 8;
            const float* bp = Brow + kk * 32 + g * 8;
            float4 a0 = *(const float4*)ap, a1 = *(const float4*)(ap + 4);
            float4 b0 = *(const float4*)bp, b1 = *(const float4*)(bp + 4);
            uint4 hv;
            hv.x = cvt_pk_bf16(fmaxf(a0.x + b0.x, 0.f), fmaxf(a0.y + b0.y, 0.f));
            hv.y = cvt_pk_bf16(fmaxf(a0.z + b0.z, 0.f), fmaxf(a0.w + b0.w, 0.f));
            hv.z = cvt_pk_bf16(fmaxf(a1.x + b1.x, 0.f), fmaxf(a1.y + b1.y, 0.f));
            hv.w = cvt_pk_bf16(fmaxf(a1.z + b1.z, 0.f), fmaxf(a1.w + b1.w, 0.f));
            *(uint4*)(Hb + (size_t)(w * 8 + kk) * 1024 + l * 16) = hv;
        }
    }
    __syncthreads();   // H1 published (also drains stage(0)/stage(1) -> landed)

    float4 bv[4];
    #pragma unroll
    for (int tti = 0; tti < 4; ++tti)
        bv[tti] = *(const float4*)(gb2 + w * 64 + tti * 16 + g * 4);

    f32x4 acc[4][4];
    #pragma unroll
    for (int pg = 0; pg < 4; ++pg)
        #pragma unroll
        for (int tti = 0; tti < 4; ++tti)
            acc[pg][tti] = (f32x4){0.f, 0.f, 0.f, 0.f};

    #pragma unroll
    for (int s = 0; s < 24; ++s) {
        const int L = s >> 3, kk = s & 7;
        // entry wait: W(s) landed. Steady state keeps 4 newest (stage s+1) in flight.
        if (s == 23) {
            asm volatile("s_waitcnt vmcnt(0)" ::: "memory");
        } else if (s > 0) {
            asm volatile("s_waitcnt vmcnt(4)" ::: "memory");
        }
        // per-layer bias reload (after entry wait; drained by next step's vmcnt(4))
        if (kk == 0 && L == 1) {
            #pragma unroll
            for (int tti = 0; tti < 4; ++tti)
                bv[tti] = *(const float4*)(gb3 + w * 64 + tti * 16 + g * 4);
        }
        if (kk == 0 && L == 2) {
            #pragma unroll
            for (int tti = 0; tti < 4; ++tti)
                bv[tti] = *(const float4*)(gb4 + w * 64 + tti * 16 + g * 4);
        }
        if (s + 2 < 24) stage(s + 2);

        short8 Wr[4], Hr[4];
        #pragma unroll
        for (int i = 0; i < 4; ++i)
            Wr[i] = *(const short8*)(Wb + (s % 3) * 16384 + (w * 4 + i) * 1024 + l * 16);
        #pragma unroll
        for (int pg = 0; pg < 4; ++pg)
            Hr[pg] = *(const short8*)(Hb + (size_t)(pg * 8 + kk) * 1024 + l * 16);
        #pragma unroll
        for (int pg = 0; pg < 4; ++pg)
            #pragma unroll
            for (int tti = 0; tti < 4; ++tti)
                acc[pg][tti] = mfma16(Wr[tti], Hr[pg], acc[pg][tti]);

        if (kk == 7) {
            if (L < 2) {
                __builtin_amdgcn_s_barrier();   // all H reads of layer L done
                // scatter relu(acc+bias) -> next-layer frags (R13-verified mapping)
                #pragma unroll
                for (int pg = 0; pg < 4; ++pg) {
                    #pragma unroll
                    for (int tti = 0; tti < 4; ++tti) {
                        uint2 q;
                        q.x = cvt_pk_bf16(fmaxf(acc[pg][tti][0] + bv[tti].x, 0.f),
                                          fmaxf(acc[pg][tti][1] + bv[tti].y, 0.f));
                        q.y = cvt_pk_bf16(fmaxf(acc[pg][tti][2] + bv[tti].z, 0.f),
                                          fmaxf(acc[pg][tti][3] + bv[tti].w, 0.f));
                        int kk2 = w * 2 + (tti >> 1);
                        int dlane = ((tti & 1) * 2 + (g >> 1)) * 16 + c;
                        *(uint2*)(Hb + (size_t)(pg * 8 + kk2) * 1024 +
                                  dlane * 16 + (g & 1) * 8) = q;
                    }
                }
                asm volatile("s_waitcnt lgkmcnt(0)" ::: "memory");
                __builtin_amdgcn_s_barrier();   // next layer's H published
                #pragma unroll
                for (int pg = 0; pg < 4; ++pg)
                    #pragma unroll
                    for (int tti = 0; tti < 4; ++tti)
                        acc[pg][tti] = (f32x4){0.f, 0.f, 0.f, 0.f};
            } else {
                // final layer: relu + pair-sum (R13-verified), 4 partials per cell
                #pragma unroll
                for (int tti = 0; tti < 4; ++tti) {
                    float s0 = 0.f, s1 = 0.f, s2 = 0.f, s3 = 0.f;
                    #pragma unroll
                    for (int pg = 0; pg < 4; ++pg) {
                        s0 += fmaxf(acc[pg][tti][0] + bv[tti].x, 0.f);
                        s1 += fmaxf(acc[pg][tti][1] + bv[tti].y, 0.f);
                        s2 += fmaxf(acc[pg][tti][2] + bv[tti].z, 0.f);
                        s3 += fmaxf(acc[pg][tti][3] + bv[tti].w, 0.f);
                    }
                    #pragma unroll
                    for (int d = 1; d < 16; d <<= 1) {
                        s0 += __shfl_xor(s0, d); s1 += __shfl_xor(s1, d);
                        s2 += __shfl_xor(s2, d); s3 += __shfl_xor(s3, d);
                    }
                    if (c == 0) {
                        float4 o = {s0, s1, s2, s3};
                        *(float4*)(xf + ((size_t)bqs * 4 + quarter) * 256 +
                                   w * 64 + tti * 16 + g * 4) = o;
                    }
                }
            }
        }
    }
}

// ---------------- kernel 4: f-MLP via MFMA + sigmoid + MSE loss (verified, unchanged) ---
__launch_bounds__(512, 1)
__global__ void k4_f(const float* __restrict__ xf,
                     const unsigned short* __restrict__ wff,
                     const unsigned short* __restrict__ wf3,
                     const float* __restrict__ fb1, const float* __restrict__ fb2,
                     const float* __restrict__ fb3,
                     const float* __restrict__ fw4, const float* __restrict__ fb4,
                     const int* __restrict__ sy, const int* __restrict__ qy,
                     float* __restrict__ out) {
    __shared__ short Hf[16384];
    __shared__ float bs[512];
    __shared__ float bs3[32];
    __shared__ float y3[64][32];
    int bid = blockIdx.x;
    int t = threadIdx.x;
    int w = t >> 6, l = t & 63;
    int g = l >> 4, c = l & 15;
    char* Hb = (char*)Hf;
    const char* wfb = (const char*)wff;

    bs[t & 511] = (t < 256) ? fb1[t] : fb2[t - 256];
    if (t < 32) bs3[t] = (t < 29) ? fb3[t] : 0.0f;

    for (int fi = w; fi < 32; fi += 8) {
        int m = fi >> 3, kk = fi & 7;
        int row = bid * 64 + m * 16 + c;
        if (row > 599) row = 599;
        const float* xr = xf + (size_t)row * 1024;
        int kb = kk * 32 + g * 8;
        float v[8];
        #pragma unroll
        for (int j = 0; j < 8; ++j) {
            int f = kb + j;
            v[j] = xr[f] + xr[256 + f] + xr[512 + f] + xr[768 + f];
        }
        uint4 hv;
        hv.x = cvt_pk_bf16(v[0], v[1]);
        hv.y = cvt_pk_bf16(v[2], v[3]);
        hv.z = cvt_pk_bf16(v[4], v[5]);
        hv.w = cvt_pk_bf16(v[6], v[7]);
        *(uint4*)(Hb + (size_t)(m * 8 + kk) * 1024 + l * 16) = hv;
    }
    __syncthreads();

    int wp = w >> 2, wn = w & 3;
    short8 wcur[4];
    #pragma unroll
    for (int tti = 0; tti < 4; ++tti)
        wcur[tti] = *(const short8*)(wfb + (size_t)(wn * 4 + tti) * 8192 + l * 16);

    #pragma unroll 1
    for (int L = 0; L < 2; ++L) {
        f32x4 acc[2][4];
        #pragma unroll
        for (int pg = 0; pg < 2; ++pg)
            #pragma unroll
            for (int tti = 0; tti < 4; ++tti)
                acc[pg][tti] = (f32x4){0.f, 0.f, 0.f, 0.f};

        #pragma unroll
        for (int kk = 0; kk < 8; ++kk) {
            int s = L * 8 + kk + 1; if (s > 15) s = 15;
            int Ln = s >> 3, kn = s & 7;
            short8 wnxt[4];
            #pragma unroll
            for (int tti = 0; tti < 4; ++tti)
                wnxt[tti] = *(const short8*)(wfb +
                    (size_t)(Ln * 16 + wn * 4 + tti) * 8192 + kn * 1024 + l * 16);
            #pragma unroll
            for (int pg = 0; pg < 2; ++pg) {
                short8 h = *(const short8*)(Hb +
                    (size_t)((wp * 2 + pg) * 8 + kk) * 1024 + l * 16);
                #pragma unroll
                for (int tti = 0; tti < 4; ++tti)
                    acc[pg][tti] = mfma16(wcur[tti], h, acc[pg][tti]);
            }
            #pragma unroll
            for (int tti = 0; tti < 4; ++tti) wcur[tti] = wnxt[tti];
        }

        float4 bv[4];
        #pragma unroll
        for (int tti = 0; tti < 4; ++tti)
            bv[tti] = *(const float4*)(bs + L * 256 + wn * 64 + tti * 16 + g * 4);

        __syncthreads();
        #pragma unroll
        for (int pg = 0; pg < 2; ++pg) {
            int m = wp * 2 + pg;
            #pragma unroll
            for (int tti = 0; tti < 4; ++tti) {
                uint2 q;
                q.x = cvt_pk_bf16(fmaxf(acc[pg][tti][0] + bv[tti].x, 0.f),
                                  fmaxf(acc[pg][tti][1] + bv[tti].y, 0.f));
                q.y = cvt_pk_bf16(fmaxf(acc[pg][tti][2] + bv[tti].z, 0.f),
                                  fmaxf(acc[pg][tti][3] + bv[tti].w, 0.f));
                int kk2 = wn * 2 + (tti >> 1);
                int dlane = ((tti & 1) * 2 + (g >> 1)) * 16 + c;
                *(uint2*)(Hb + (size_t)(m * 8 + kk2) * 1024 + dlane * 16 + (g & 1) * 8) = q;
            }
        }
        __syncthreads();
    }

    {
        int m = w >> 1, tt = w & 1;
        f32x4 a3 = {0.f, 0.f, 0.f, 0.f};
        #pragma unroll
        for (int kk = 0; kk < 8; ++kk) {
            short8 wv = *(const short8*)((const char*)wf3 +
                (size_t)(tt * 8 + kk) * 1024 + l * 16);
            short8 h = *(const short8*)(Hb + (size_t)(m * 8 + kk) * 1024 + l * 16);
            a3 = mfma16(wv, h, a3);
        }
        #pragma unroll
        for (int r = 0; r < 4; ++r) {
            int oc = tt * 16 + g * 4 + r;
            float v = a3[r] + bs3[oc];
            y3[m * 16 + c][oc] = v > 0.f ? v : 0.f;
        }
    }
    __syncthreads();

    if (t < 64) {
        int bqs = bid * 64 + t;
        if (bqs < 600) {
            float z = fb4[0];
            #pragma unroll
            for (int k = 0; k < 29; ++k) z += y3[t][k] * fw4[k];
            float score = 1.0f / (1.0f + __expf(-z));
            int b = bqs / 75, rem = bqs % 75, qi = rem / 5, si = rem % 5;
            float label = (sy[b * NS + si] == qy[b * NQ + qi]) ? 1.0f : 0.0f;
            float d = label - score;
            atomicAdd(out, d * d * 0.125f);
        }
    }
}

// ---------------- launch ----------------
extern "C" void kernel_launch(void* const* d_in, const int* in_sizes, int n_in,
                              void* d_out, int out_size, void* d_ws, size_t ws_size,
                              hipStream_t stream) {
    const float* sup = (const float*)d_in[0];
    const float* qry = (const float*)d_in[1];
    const int*   sy  = (const int*)d_in[2];
    const int*   qy  = (const int*)d_in[3];
    const float* gw1 = (const float*)d_in[4];
    const float* gb1 = (const float*)d_in[5];
    const float* gw2 = (const float*)d_in[6];
    const float* gb2 = (const float*)d_in[7];
    const float* gw3 = (const float*)d_in[8];
    const float* gb3 = (const float*)d_in[9];
    const float* gw4 = (const float*)d_in[10];
    const float* gb4 = (const float*)d_in[11];
    const float* fw1 = (const float*)d_in[12];
    const float* fb1 = (const float*)d_in[13];
    const float* fw2 = (const float*)d_in[14];
    const float* fb2 = (const float*)d_in[15];
    const float* fw3 = (const float*)d_in[16];
    const float* fb3 = (const float*)d_in[17];
    const float* fw4 = (const float*)d_in[18];
    const float* fb4 = (const float*)d_in[19];

    float* ws = (float*)d_ws;
    float* A  = ws + A_OFF_F;
    float* B  = ws + B_OFF_F;
    float* xf = ws + XF_OFF_F;
    unsigned short* wf  = (unsigned short*)((char*)d_ws + WF_OFF_BYTES);
    unsigned short* wf1 = (unsigned short*)((char*)d_ws + WF1_OFF_BYTES);
    unsigned short* wff = (unsigned short*)((char*)d_ws + WFF_OFF_BYTES);
    unsigned short* wf3 = (unsigned short*)((char*)d_ws + WF3_OFF_BYTES);
    float* out = (float*)d_out;

    kA<<<32, 64, 0, stream>>>(gw1, wf1);
    kB<<<181, 256, 0, stream>>>(sup, qry, wf1, gb1, gw2, gw3, gw4,
                                fw1, fw2, fw3, ws, wf, wff, wf3, out);
    k3_g<<<2400, 256, 0, stream>>>(A, B, wf, gb2, gb3, gb4, xf);
    k4_f<<<10, 512, 0, stream>>>(xf, wff, wf3, fb1, fb2, fb3, fw4, fb4, sy, qy, out);
}

// Round 17
// 110.886 us; speedup vs baseline: 1.1028x; 1.1028x over previous
//
#include <hip/hip_runtime.h>

// ---------------- types / helpers ----------------
typedef __attribute__((ext_vector_type(8))) __bf16 bf16x8;
typedef __attribute__((ext_vector_type(8))) short short8;
typedef __attribute__((ext_vector_type(4))) float f32x4;
typedef unsigned int u32;

static __device__ __forceinline__ unsigned short f2bf(float f) {
    u32 u = __float_as_uint(f);
    u += 0x7FFFu + ((u >> 16) & 1u);
    return (unsigned short)(u >> 16);
}
static __device__ __forceinline__ u32 cvt_pk_bf16(float lo, float hi) {
    u32 r;
    asm("v_cvt_pk_bf16_f32 %0, %1, %2" : "=v"(r) : "v"(lo), "v"(hi));
    return r;
}
static __device__ __forceinline__ bf16x8 as_bf16x8(short8 v) {
    return __builtin_bit_cast(bf16x8, v);
}
static __device__ __forceinline__ f32x4 mfma16(short8 a, short8 b, f32x4 c) {
    return __builtin_amdgcn_mfma_f32_16x16x32_bf16(as_bf16x8(a), as_bf16x8(b), c, 0, 0, 0);
}

// problem sizes
#define NB 8
#define NS 5
#define NQ 15
// ws layout (floats / bytes)
#define A_OFF_F 0
#define B_OFF_F (640*256)                        // 163840
#define XF_OFF_F (B_OFF_F + 1920*256)            // 655360
#define WF_OFF_BYTES ((XF_OFF_F + 600*1024)*4)   // 5079040, 16B aligned
#define WF1_OFF_BYTES (WF_OFF_BYTES + 48*8192)   // W1 frags (32 x 9216)
#define WFF_OFF_BYTES (WF1_OFF_BYTES + 32*9216)  // fw1/fw2 frags (32 x 8192)
#define WF3_OFF_BYTES (WFF_OFF_BYTES + 32*8192)  // fw3 frags (2 x 8192)

// ---------------- kernel A: W1 fragments only (needed by kB) ----------------
__global__ void kA(const float* __restrict__ w1, unsigned short* __restrict__ wf1) {
    int c1 = blockIdx.x;               // S*16 + tt
    int l = threadIdx.x;
    int S = c1 >> 4, tt = c1 & 15;
    int nn = tt * 16 + (l & 15);
    for (int kk = 0; kk < 9; ++kk) {
        int k0 = kk * 32 + (l >> 4) * 8;
        short8 ov;
        #pragma unroll
        for (int j = 0; j < 8; ++j) {
            int kb = k0 + j;
            float v = (kb < 258) ? w1[(size_t)(S * 258 + kb) * 256 + nn] : 0.0f;
            ov[j] = (short)f2bf(v);
        }
        *(short8*)((char*)wf1 + (size_t)c1 * 9216 + kk * 1024 + l * 16) = ov;
    }
}

// ---------------- kernel B: layer-1 via MFMA (1 cell/block) + all later-stage frags ----
// (verified round 15, unchanged)
__global__ void kB(const float* __restrict__ sup, const float* __restrict__ qry,
                   const unsigned short* __restrict__ wf1, const float* __restrict__ gb1,
                   const float* __restrict__ w2, const float* __restrict__ w3,
                   const float* __restrict__ w4,
                   const float* __restrict__ fw1, const float* __restrict__ fw2,
                   const float* __restrict__ fw3,
                   float* __restrict__ ws, unsigned short* __restrict__ wf,
                   unsigned short* __restrict__ wff, unsigned short* __restrict__ wf3,
                   float* __restrict__ out) {
    __shared__ short Xf[4608];        // 9 KB
    int bid = blockIdx.x;
    int t = threadIdx.x;
    int w = t >> 6, l = t & 63;
    int g = l >> 4, c = l & 15;

    if (bid >= 160) {
        if (bid < 172) {              // g-weight frags
            int cid = (bid - 160) * 4 + w;   // 0..47 = L*16+tt
            int L = cid >> 4, tt = cid & 15;
            const float* W = (L == 0) ? w2 : ((L == 1) ? w3 : w4);
            int nn = tt * 16 + (l & 15);
            #pragma unroll
            for (int kk = 0; kk < 8; ++kk) {
                int k0 = kk * 32 + (l >> 4) * 8;
                short8 ov;
                #pragma unroll
                for (int j = 0; j < 8; ++j)
                    ov[j] = (short)f2bf(W[(size_t)(k0 + j) * 256 + nn]);
                *(short8*)((char*)wf + (size_t)cid * 8192 + kk * 1024 + l * 16) = ov;
            }
        } else if (bid == 172) {      // fw3 frags + out init
            if (w < 2) {
                int tt = w;
                int nn = tt * 16 + (l & 15);
                #pragma unroll
                for (int kk = 0; kk < 8; ++kk) {
                    int k0 = kk * 32 + (l >> 4) * 8;
                    short8 ov;
                    #pragma unroll
                    for (int j = 0; j < 8; ++j) {
                        float v = (nn < 29) ? fw3[(size_t)(k0 + j) * 29 + nn] : 0.0f;
                        ov[j] = (short)f2bf(v);
                    }
                    *(short8*)((char*)wf3 + (size_t)tt * 8192 + kk * 1024 + l * 16) = ov;
                }
            } else if (w == 2 && l == 0) {
                out[0] = 0.0f;
            }
        } else {                      // fw1/fw2 frags
            int cid = (bid - 173) * 4 + w;   // 0..31 = Lf*16+tt
            int Lf = cid >> 4, tt = cid & 15;
            const float* W = (Lf == 0) ? fw1 : fw2;
            int nn = tt * 16 + (l & 15);
            #pragma unroll
            for (int kk = 0; kk < 8; ++kk) {
                int k0 = kk * 32 + (l >> 4) * 8;
                short8 ov;
                #pragma unroll
                for (int j = 0; j < 8; ++j)
                    ov[j] = (short)f2bf(W[(size_t)(k0 + j) * 256 + nn]);
                *(short8*)((char*)wff + (size_t)cid * 8192 + kk * 1024 + l * 16) = ov;
            }
        }
        return;
    }

    // ---- layer-1 path: one cell, 16 rows (single m-frag)
    bool isA = (bid < 40);
    int S = isA ? 0 : 1;
    int cell = isA ? bid : (bid - 40);
    const float* src = (isA ? sup : qry) + (size_t)cell * 4096;
    float* dst0 = ws + (isA ? A_OFF_F : B_OFF_F);
    char* Xb = (char*)Xf;

    // stage X frags (kk split across waves): k = kk*32+g*8+j, n = c
    for (int kk = w; kk < 9; kk += 4) {
        int kbase = kk * 32 + g * 8;
        float v[8];
        #pragma unroll
        for (int j = 0; j < 8; ++j) {
            int kb = kbase + j;
            float x;
            if (kb < 256)       x = src[(size_t)kb * 16 + c];
            else if (kb == 256) x = (float)(c >> 2) * 0.25f;
            else if (kb == 257) x = (float)(c & 3) * 0.25f;
            else                x = 0.0f;
            v[j] = x;
        }
        uint4 hv;
        hv.x = cvt_pk_bf16(v[0], v[1]);
        hv.y = cvt_pk_bf16(v[2], v[3]);
        hv.z = cvt_pk_bf16(v[4], v[5]);
        hv.w = cvt_pk_bf16(v[6], v[7]);
        *(uint4*)(Xb + (size_t)kk * 1024 + l * 16) = hv;
    }
    __syncthreads();

    // wave w -> outcols [w*64, +64)
    const char* wbase = (const char*)wf1 + (size_t)(S * 16 + w * 4) * 9216;
    short8 wcur[4];
    #pragma unroll
    for (int tti = 0; tti < 4; ++tti)
        wcur[tti] = *(const short8*)(wbase + (size_t)tti * 9216 + l * 16);

    f32x4 acc[4];
    #pragma unroll
    for (int tti = 0; tti < 4; ++tti) acc[tti] = (f32x4){0.f, 0.f, 0.f, 0.f};

    #pragma unroll
    for (int kk = 0; kk < 9; ++kk) {
        int kn = kk + 1; if (kn > 8) kn = 8;
        short8 wnxt[4];
        #pragma unroll
        for (int tti = 0; tti < 4; ++tti)
            wnxt[tti] = *(const short8*)(wbase + (size_t)tti * 9216 + kn * 1024 + l * 16);
        short8 h = *(const short8*)(Xb + (size_t)kk * 1024 + l * 16);
        #pragma unroll
        for (int tti = 0; tti < 4; ++tti)
            acc[tti] = mfma16(wcur[tti], h, acc[tti]);
        #pragma unroll
        for (int tti = 0; tti < 4; ++tti) wcur[tti] = wnxt[tti];
    }

    // epilogue: row = cell*16 + c, col = w*64 + tti*16 + g*4 + r
    #pragma unroll
    for (int tti = 0; tti < 4; ++tti) {
        int col0 = w * 64 + tti * 16 + g * 4;
        float4 bv = {0.f, 0.f, 0.f, 0.f};
        if (S == 0) bv = *(const float4*)(gb1 + col0);
        int row = cell * 16 + c;
        float4 o;
        o.x = acc[tti][0] + bv.x;
        o.y = acc[tti][1] + bv.y;
        o.z = acc[tti][2] + bv.z;
        o.w = acc[tti][3] + bv.w;
        *(float4*)(dst0 + (size_t)row * 256 + col0) = o;
    }
}

// ---------------- kernel 3: g-MLP layers 2..4 + pair-sum (R12/R15 verified config) ------
// grid = 1200 blocks = (cell, half): 128 pairs. 512 threads = 8 waves (wp x wn = 2x4).
// 83.4 us steady-state, reproduced 5 rounds. 4 waves/SIMD; unified reg budget
// (VGPR 64 + AGPR 64 = 128) exactly saturates the 4-wave cap -> no deeper
// source-level pipelining is expressible without occupancy or spill regressions
// (R13, R16 confirmed both failure modes).
__launch_bounds__(512, 4)
__global__ void k3_g(const float* __restrict__ wsA, const float* __restrict__ wsB,
                     const unsigned short* __restrict__ wf,
                     const float* __restrict__ gb2, const float* __restrict__ gb3,
                     const float* __restrict__ gb4, float* __restrict__ xf) {
    __shared__ short Hf[32768];   // 64 KB: frag(m,kk) at (m*8+kk)*1024 bytes, m 0..7
    __shared__ float bs[768];
    int bid = blockIdx.x;
    int bqs = bid >> 1, half = bid & 1;
    int b = bqs / 75, rem = bqs % 75, qi = rem / 5, si = rem % 5;
    int t = threadIdx.x;
    int w = t >> 6, l = t & 63;
    int g = l >> 4, c = l & 15;
    int wp = w >> 2, wn = w & 3;
    char* Hb = (char*)Hf;
    const char* wfb = (const char*)wf;

    if (t < 256) { bs[t] = gb2[t]; bs[256 + t] = gb3[t]; bs[512 + t] = gb4[t]; }

    short8 wcur[4];
    #pragma unroll
    for (int tti = 0; tti < 4; ++tti)
        wcur[tti] = *(const short8*)(wfb + (size_t)(wn * 4 + tti) * 8192 + l * 16);

    {
        const float* Arow = wsA + (size_t)(b * NS + si) * 4096 + c * 256;
        const float* Brow = wsB + (size_t)(b * NQ + qi) * 4096 + (half * 8 + w) * 256;
        #pragma unroll
        for (int kk = 0; kk < 8; ++kk) {
            const float* ap = Arow + kk * 32 + g * 8;
            const float* bp = Brow + kk * 32 + g * 8;
            float4 a0 = *(const float4*)ap, a1 = *(const float4*)(ap + 4);
            float4 b0 = *(const float4*)bp, b1 = *(const float4*)(bp + 4);
            uint4 hv;
            hv.x = cvt_pk_bf16(fmaxf(a0.x + b0.x, 0.f), fmaxf(a0.y + b0.y, 0.f));
            hv.y = cvt_pk_bf16(fmaxf(a0.z + b0.z, 0.f), fmaxf(a0.w + b0.w, 0.f));
            hv.z = cvt_pk_bf16(fmaxf(a1.x + b1.x, 0.f), fmaxf(a1.y + b1.y, 0.f));
            hv.w = cvt_pk_bf16(fmaxf(a1.z + b1.z, 0.f), fmaxf(a1.w + b1.w, 0.f));
            *(uint4*)(Hb + (size_t)(w * 8 + kk) * 1024 + l * 16) = hv;
        }
    }
    __syncthreads();

    #pragma unroll 1
    for (int L = 0; L < 3; ++L) {
        f32x4 acc[4][4];
        #pragma unroll
        for (int pg = 0; pg < 4; ++pg)
            #pragma unroll
            for (int tti = 0; tti < 4; ++tti)
                acc[pg][tti] = (f32x4){0.f, 0.f, 0.f, 0.f};

        #pragma unroll
        for (int kk = 0; kk < 8; ++kk) {
            int s = L * 8 + kk + 1; if (s > 23) s = 23;
            int Ln = s >> 3, kn = s & 7;
            short8 wnxt[4];
            #pragma unroll
            for (int tti = 0; tti < 4; ++tti)
                wnxt[tti] = *(const short8*)(wfb +
                    (size_t)(Ln * 16 + wn * 4 + tti) * 8192 + kn * 1024 + l * 16);
            #pragma unroll
            for (int pg = 0; pg < 4; ++pg) {
                short8 h = *(const short8*)(Hb +
                    (size_t)((wp * 4 + pg) * 8 + kk) * 1024 + l * 16);
                #pragma unroll
                for (int tti = 0; tti < 4; ++tti)
                    acc[pg][tti] = mfma16(wcur[tti], h, acc[pg][tti]);
            }
            #pragma unroll
            for (int tti = 0; tti < 4; ++tti) wcur[tti] = wnxt[tti];
        }

        float4 bv[4];
        #pragma unroll
        for (int tti = 0; tti < 4; ++tti)
            bv[tti] = *(const float4*)(bs + L * 256 + wn * 64 + tti * 16 + g * 4);

        if (L < 2) {
            __syncthreads();
            #pragma unroll
            for (int pg = 0; pg < 4; ++pg) {
                int m = wp * 4 + pg;
                #pragma unroll
                for (int tti = 0; tti < 4; ++tti) {
                    uint2 q;
                    q.x = cvt_pk_bf16(fmaxf(acc[pg][tti][0] + bv[tti].x, 0.f),
                                      fmaxf(acc[pg][tti][1] + bv[tti].y, 0.f));
                    q.y = cvt_pk_bf16(fmaxf(acc[pg][tti][2] + bv[tti].z, 0.f),
                                      fmaxf(acc[pg][tti][3] + bv[tti].w, 0.f));
                    int kk2 = wn * 2 + (tti >> 1);
                    int dlane = ((tti & 1) * 2 + (g >> 1)) * 16 + c;
                    *(uint2*)(Hb + (size_t)(m * 8 + kk2) * 1024 + dlane * 16 + (g & 1) * 8) = q;
                }
            }
            __syncthreads();
        } else {
            #pragma unroll
            for (int tti = 0; tti < 4; ++tti) {
                float s0 = 0.f, s1 = 0.f, s2 = 0.f, s3 = 0.f;
                #pragma unroll
                for (int pg = 0; pg < 4; ++pg) {
                    s0 += fmaxf(acc[pg][tti][0] + bv[tti].x, 0.f);
                    s1 += fmaxf(acc[pg][tti][1] + bv[tti].y, 0.f);
                    s2 += fmaxf(acc[pg][tti][2] + bv[tti].z, 0.f);
                    s3 += fmaxf(acc[pg][tti][3] + bv[tti].w, 0.f);
                }
                #pragma unroll
                for (int d = 1; d < 16; d <<= 1) {
                    s0 += __shfl_xor(s0, d); s1 += __shfl_xor(s1, d);
                    s2 += __shfl_xor(s2, d); s3 += __shfl_xor(s3, d);
                }
                if (c == 0) {
                    float4 o = {s0, s1, s2, s3};
                    *(float4*)(xf + (((size_t)bqs * 2 + half) * 2 + wp) * 256 +
                               wn * 64 + tti * 16 + g * 4) = o;
                }
            }
        }
    }
}

// ---------------- kernel 4: f-MLP via MFMA + sigmoid + MSE loss (verified, unchanged) ---
__launch_bounds__(512, 1)
__global__ void k4_f(const float* __restrict__ xf,
                     const unsigned short* __restrict__ wff,
                     const unsigned short* __restrict__ wf3,
                     const float* __restrict__ fb1, const float* __restrict__ fb2,
                     const float* __restrict__ fb3,
                     const float* __restrict__ fw4, const float* __restrict__ fb4,
                     const int* __restrict__ sy, const int* __restrict__ qy,
                     float* __restrict__ out) {
    __shared__ short Hf[16384];   // 32 KB: frag(m,kk) at (m*8+kk)*1024, m 0..3
    __shared__ float bs[512];
    __shared__ float bs3[32];
    __shared__ float y3[64][32];
    int bid = blockIdx.x;
    int t = threadIdx.x;
    int w = t >> 6, l = t & 63;
    int g = l >> 4, c = l & 15;
    char* Hb = (char*)Hf;
    const char* wfb = (const char*)wff;

    bs[t & 511] = (t < 256) ? fb1[t] : fb2[t - 256];
    if (t < 32) bs3[t] = (t < 29) ? fb3[t] : 0.0f;

    for (int fi = w; fi < 32; fi += 8) {
        int m = fi >> 3, kk = fi & 7;
        int row = bid * 64 + m * 16 + c;
        if (row > 599) row = 599;
        const float* xr = xf + (size_t)row * 1024;
        int kb = kk * 32 + g * 8;
        float v[8];
        #pragma unroll
        for (int j = 0; j < 8; ++j) {
            int f = kb + j;
            v[j] = xr[f] + xr[256 + f] + xr[512 + f] + xr[768 + f];
        }
        uint4 hv;
        hv.x = cvt_pk_bf16(v[0], v[1]);
        hv.y = cvt_pk_bf16(v[2], v[3]);
        hv.z = cvt_pk_bf16(v[4], v[5]);
        hv.w = cvt_pk_bf16(v[6], v[7]);
        *(uint4*)(Hb + (size_t)(m * 8 + kk) * 1024 + l * 16) = hv;
    }
    __syncthreads();

    int wp = w >> 2, wn = w & 3;
    short8 wcur[4];
    #pragma unroll
    for (int tti = 0; tti < 4; ++tti)
        wcur[tti] = *(const short8*)(wfb + (size_t)(wn * 4 + tti) * 8192 + l * 16);

    #pragma unroll 1
    for (int L = 0; L < 2; ++L) {
        f32x4 acc[2][4];
        #pragma unroll
        for (int pg = 0; pg < 2; ++pg)
            #pragma unroll
            for (int tti = 0; tti < 4; ++tti)
                acc[pg][tti] = (f32x4){0.f, 0.f, 0.f, 0.f};

        #pragma unroll
        for (int kk = 0; kk < 8; ++kk) {
            int s = L * 8 + kk + 1; if (s > 15) s = 15;
            int Ln = s >> 3, kn = s & 7;
            short8 wnxt[4];
            #pragma unroll
            for (int tti = 0; tti < 4; ++tti)
                wnxt[tti] = *(const short8*)(wfb +
                    (size_t)(Ln * 16 + wn * 4 + tti) * 8192 + kn * 1024 + l * 16);
            #pragma unroll
            for (int pg = 0; pg < 2; ++pg) {
                short8 h = *(const short8*)(Hb +
                    (size_t)((wp * 2 + pg) * 8 + kk) * 1024 + l * 16);
                #pragma unroll
                for (int tti = 0; tti < 4; ++tti)
                    acc[pg][tti] = mfma16(wcur[tti], h, acc[pg][tti]);
            }
            #pragma unroll
            for (int tti = 0; tti < 4; ++tti) wcur[tti] = wnxt[tti];
        }

        float4 bv[4];
        #pragma unroll
        for (int tti = 0; tti < 4; ++tti)
            bv[tti] = *(const float4*)(bs + L * 256 + wn * 64 + tti * 16 + g * 4);

        __syncthreads();
        #pragma unroll
        for (int pg = 0; pg < 2; ++pg) {
            int m = wp * 2 + pg;
            #pragma unroll
            for (int tti = 0; tti < 4; ++tti) {
                uint2 q;
                q.x = cvt_pk_bf16(fmaxf(acc[pg][tti][0] + bv[tti].x, 0.f),
                                  fmaxf(acc[pg][tti][1] + bv[tti].y, 0.f));
                q.y = cvt_pk_bf16(fmaxf(acc[pg][tti][2] + bv[tti].z, 0.f),
                                  fmaxf(acc[pg][tti][3] + bv[tti].w, 0.f));
                int kk2 = wn * 2 + (tti >> 1);
                int dlane = ((tti & 1) * 2 + (g >> 1)) * 16 + c;
                *(uint2*)(Hb + (size_t)(m * 8 + kk2) * 1024 + dlane * 16 + (g & 1) * 8) = q;
            }
        }
        __syncthreads();
    }

    {
        int m = w >> 1, tt = w & 1;
        f32x4 a3 = {0.f, 0.f, 0.f, 0.f};
        #pragma unroll
        for (int kk = 0; kk < 8; ++kk) {
            short8 wv = *(const short8*)((const char*)wf3 +
                (size_t)(tt * 8 + kk) * 1024 + l * 16);
            short8 h = *(const short8*)(Hb + (size_t)(m * 8 + kk) * 1024 + l * 16);
            a3 = mfma16(wv, h, a3);
        }
        #pragma unroll
        for (int r = 0; r < 4; ++r) {
            int oc = tt * 16 + g * 4 + r;
            float v = a3[r] + bs3[oc];
            y3[m * 16 + c][oc] = v > 0.f ? v : 0.f;
        }
    }
    __syncthreads();

    if (t < 64) {
        int bqs = bid * 64 + t;
        if (bqs < 600) {
            float z = fb4[0];
            #pragma unroll
            for (int k = 0; k < 29; ++k) z += y3[t][k] * fw4[k];
            float score = 1.0f / (1.0f + __expf(-z));
            int b = bqs / 75, rem = bqs % 75, qi = rem / 5, si = rem % 5;
            float label = (sy[b * NS + si] == qy[b * NQ + qi]) ? 1.0f : 0.0f;
            float d = label - score;
            atomicAdd(out, d * d * 0.125f);
        }
    }
}

// ---------------- launch ----------------
extern "C" void kernel_launch(void* const* d_in, const int* in_sizes, int n_in,
                              void* d_out, int out_size, void* d_ws, size_t ws_size,
                              hipStream_t stream) {
    const float* sup = (const float*)d_in[0];
    const float* qry = (const float*)d_in[1];
    const int*   sy  = (const int*)d_in[2];
    const int*   qy  = (const int*)d_in[3];
    const float* gw1 = (const float*)d_in[4];
    const float* gb1 = (const float*)d_in[5];
    const float* gw2 = (const float*)d_in[6];
    const float* gb2 = (const float*)d_in[7];
    const float* gw3 = (const float*)d_in[8];
    const float* gb3 = (const float*)d_in[9];
    const float* gw4 = (const float*)d_in[10];
    const float* gb4 = (const float*)d_in[11];
    const float* fw1 = (const float*)d_in[12];
    const float* fb1 = (const float*)d_in[13];
    const float* fw2 = (const float*)d_in[14];
    const float* fb2 = (const float*)d_in[15];
    const float* fw3 = (const float*)d_in[16];
    const float* fb3 = (const float*)d_in[17];
    const float* fw4 = (const float*)d_in[18];
    const float* fb4 = (const float*)d_in[19];

    float* ws = (float*)d_ws;
    float* A  = ws + A_OFF_F;
    float* B  = ws + B_OFF_F;
    float* xf = ws + XF_OFF_F;
    unsigned short* wf  = (unsigned short*)((char*)d_ws + WF_OFF_BYTES);
    unsigned short* wf1 = (unsigned short*)((char*)d_ws + WF1_OFF_BYTES);
    unsigned short* wff = (unsigned short*)((char*)d_ws + WFF_OFF_BYTES);
    unsigned short* wf3 = (unsigned short*)((char*)d_ws + WF3_OFF_BYTES);
    float* out = (float*)d_out;

    kA<<<32, 64, 0, stream>>>(gw1, wf1);
    kB<<<181, 256, 0, stream>>>(sup, qry, wf1, gb1, gw2, gw3, gw4,
                                fw1, fw2, fw3, ws, wf, wff, wf3, out);
    k3_g<<<1200, 512, 0, stream>>>(A, B, wf, gb2, gb3, gb4, xf);
    k4_f<<<10, 512, 0, stream>>>(xf, wff, wf3, fb1, fb2, fb3, fw4, fb4, sy, qy, out);
}